// Round 1
// 557.531 us; speedup vs baseline: 1.1143x; 1.1143x over previous
//
#include <hip/hip_runtime.h>
#include <hip/hip_bf16.h>

// out[M,N] = data[M,K] @ (mask*weight)[N,K]^T + bias[N];  M=8192, N=K=4096, fp32.
// R3: replace m97-structure 128-tile GEMM (797 TF, documented ~900 TF ceiling)
// with 256x256 / BK=64 / 8-wave counted-vmcnt phase schedule (T1+T2+T3/T4+T5):
//  - LDS 128 KiB double-buffer, XOR-swizzle chunk^=(row&7) (T2); linear LDS dest
//    for global_load_lds + pre-swizzled GLOBAL source + swizzled ds_read (rule 21)
//  - 4 phases / K-tile, one C-quadrant (16 MFMA) each; 2 global_load_lds per
//    phase for the NEXT tile; s_waitcnt vmcnt(4) + raw s_barrier per published
//    phase (3 barriers / 64-K); vmcnt never drains to 0 in the main loop (T4)
//  - setprio(1) around MFMA clusters (T5); bijective XCD swizzle, 512 blocks (T1)
// Proven retirement accounting: loads issued at phase p retire ~3-4 phases later,
// always >=1 barrier before their readers. k_cvt_all unchanged for attribution.

#define Mdim 8192
#define Ndim 4096
#define Kdim 4096

typedef __bf16 bf16x8 __attribute__((ext_vector_type(8)));
typedef float f32x4 __attribute__((ext_vector_type(4)));

// round-to-nearest-even fp32 -> bf16 bits
__device__ inline unsigned short f2bf(float f) {
    union { float f; unsigned u; } v;
    v.f = f;
    unsigned r = v.u + 0x7fffu + ((v.u >> 16) & 1u);
    return (unsigned short)(r >> 16);
}

__device__ inline unsigned pack2(float a, float b) {
    return (unsigned)f2bf(a) | ((unsigned)f2bf(b) << 16);
}

// async global->LDS, 16B per lane; lds_ptr per-lane = wave-uniform base + lane*16
#define GLOAD_LDS16(gp, lp)                                                     \
    __builtin_amdgcn_global_load_lds((const __attribute__((address_space(1))) void*)(gp), \
                                     (__attribute__((address_space(3))) void*)(lp), 16, 0, 0)

#define VMCNT(n)  asm volatile("s_waitcnt vmcnt(" #n ")" ::: "memory")
#define FENCE()   asm volatile("" ::: "memory")
#define BARRIER() do { FENCE(); __builtin_amdgcn_s_barrier(); FENCE(); } while (0)

// ---- fused conversion: data->bf16 and (weight*mask)->bf16, 16B I/O (unchanged) ----
__global__ __launch_bounds__(256) void k_cvt_all(const float4* __restrict__ data,
                                                 const float4* __restrict__ weight,
                                                 const float4* __restrict__ mask,
                                                 uint4* __restrict__ Abf,
                                                 uint4* __restrict__ Bbf) {
    const int NA = Mdim * (Kdim / 8);
    const int NB = Ndim * (Kdim / 8);
    const int stride = gridDim.x * blockDim.x;
    for (int i = blockIdx.x * blockDim.x + threadIdx.x; i < NA + NB; i += stride) {
        if (i < NA) {
            const size_t j2 = 2 * (size_t)i;
            float4 v0 = data[j2], v1 = data[j2 + 1];
            uint4 o;
            o.x = pack2(v0.x, v0.y); o.y = pack2(v0.z, v0.w);
            o.z = pack2(v1.x, v1.y); o.w = pack2(v1.z, v1.w);
            Abf[i] = o;
        } else {
            const size_t j = (size_t)(i - NA);
            const size_t j2 = 2 * j;
            float4 w0 = weight[j2], w1 = weight[j2 + 1];
            float4 m0 = mask[j2],   m1 = mask[j2 + 1];
            uint4 o;
            o.x = pack2(w0.x * m0.x, w0.y * m0.y);
            o.y = pack2(w0.z * m0.z, w0.w * m0.w);
            o.z = pack2(w1.x * m1.x, w1.y * m1.y);
            o.w = pack2(w1.z * m1.z, w1.w * m1.w);
            Bbf[j] = o;
        }
    }
}

// ---- bf16 MFMA GEMM: C = A * B^T + bias, 256x256 tile, counted-vmcnt pipeline ----
__global__ __launch_bounds__(512, 2) void k_gemm256(const unsigned short* __restrict__ A,
                                                    const unsigned short* __restrict__ B,
                                                    const float* __restrict__ bias,
                                                    float* __restrict__ out) {
    // [buf][A/B][256][64] bf16, 128 KiB. Physical col-chunk = logical ^ (row&7).
    __shared__ __align__(16) unsigned short sh[2 * 2 * 256 * 64];

    const int tid  = threadIdx.x;
    const int lane = tid & 63;
    const int wave = tid >> 6;

    // T1: bijective XCD swizzle, nwg=512 (divisible by 8)
    const int bid = blockIdx.x;
    const int swz = (bid & 7) * 64 + (bid >> 3);
    const int bm  = (swz & 31) * 256;   // 32 M-tiles
    const int bn  = (swz >> 5) * 256;   // 16 N-tiles; each XCD owns 2 B-panels (~4MB = L2)

    const int wm = (wave >> 2) * 128;   // 2 M-wave groups
    const int wn = (wave & 3) * 64;     // 4 N-wave groups

    // staging constants: thread t covers phys row Rb+(lane>>3), phys chunk (lane&7)
    const int rrow = lane >> 3;                      // 0..7
    const int scol = ((lane & 7) ^ rrow) * 8;        // pre-swizzled global col (ushorts)
    const int ldsl = lane * 8;                       // linear LDS (ushorts): lane*16B
    const int w8   = wave * 8;
    const int rbB  = (wave >> 2) * 64 + (wave & 3) * 8;  // B qn0 wave-chunk base row

    // fragment-read constants (16x16x32): row = base + fr, kchunk = kc + ks*4
    const int fr = lane & 15;
    const int kc = lane >> 4;
    const int po = (kc ^ (fr & 7)) * 8;              // swizzled chunk offset, ks=0 (ushorts)

#define STAGE_A(buf, k0, Rb) GLOAD_LDS16(                                        \
        A + (size_t)(bm + (Rb) + rrow) * Kdim + (k0) + scol,                     \
        sh + (buf) * 32768 + (Rb) * 64 + ldsl)
#define STAGE_B(buf, k0, Rb) GLOAD_LDS16(                                        \
        B + (size_t)(bn + (Rb) + rrow) * Kdim + (k0) + scol,                     \
        sh + (buf) * 32768 + 16384 + (Rb) * 64 + ldsl)

    f32x4 acc[8][4];
#pragma unroll
    for (int i = 0; i < 8; ++i)
#pragma unroll
        for (int j = 0; j < 4; ++j) acc[i][j] = (f32x4){0.f, 0.f, 0.f, 0.f};

    // ---- prologue: stage tile 0 into buf0, steady-state issue order ----
    STAGE_A(0, 0, 0 + w8);   STAGE_A(0, 0, 128 + w8);      // A qm0
    STAGE_B(0, 0, rbB);      STAGE_B(0, 0, rbB + 128);     // B qn0
    STAGE_A(0, 0, 64 + w8);  STAGE_A(0, 0, 192 + w8);      // A qm1
    STAGE_B(0, 0, rbB + 32); STAGE_B(0, 0, rbB + 160);     // B qn1
    VMCNT(4);          // retire G0 = {A qm0, B qn0}; A qm1/B qn1 stay in flight
    BARRIER();

#define MM(ci, cj, av, bv) \
    acc[ci][cj] = __builtin_amdgcn_mfma_f32_16x16x32_bf16(av, bv, acc[ci][cj], 0, 0, 0)

    const int NT = Kdim / 64;   // 64
    for (int t = 0; t < NT - 1; ++t) {
        const int cur  = t & 1;
        const int nxtb = cur ^ 1;
        const int k0n  = (t + 1) * 64;
        const unsigned short* pA = sh + cur * 32768 + (wm + fr) * 64;
        const unsigned short* pB = sh + cur * 32768 + 16384 + (wn + fr) * 64;

        bf16x8 a0[4][2], a1[4][2], b0[2][2], b1[2][2];

        // ---------- phase 0: quadrant (qm0, qn0) ----------
#pragma unroll
        for (int i = 0; i < 4; ++i) {
            a0[i][0] = *(const bf16x8*)(pA + i * 1024 + po);
            a0[i][1] = *(const bf16x8*)(pA + i * 1024 + (po ^ 32));
        }
#pragma unroll
        for (int j = 0; j < 2; ++j) {
            b0[j][0] = *(const bf16x8*)(pB + j * 1024 + po);
            b0[j][1] = *(const bf16x8*)(pB + j * 1024 + (po ^ 32));
        }
        STAGE_A(nxtb, k0n, 0 + w8); STAGE_A(nxtb, k0n, 128 + w8);
        VMCNT(4);                    // retires prev A qm1 (needed by phase 1 reads)
        BARRIER();
        __builtin_amdgcn_s_setprio(1);
#pragma unroll
        for (int i = 0; i < 4; ++i)
#pragma unroll
            for (int j = 0; j < 2; ++j) { MM(i, j, a0[i][0], b0[j][0]); MM(i, j, a0[i][1], b0[j][1]); }
        __builtin_amdgcn_s_setprio(0);

        // ---------- phase 1: quadrant (qm1, qn0) ----------
#pragma unroll
        for (int i = 0; i < 4; ++i) {
            a1[i][0] = *(const bf16x8*)(pA + 4096 + i * 1024 + po);
            a1[i][1] = *(const bf16x8*)(pA + 4096 + i * 1024 + (po ^ 32));
        }
        STAGE_B(nxtb, k0n, rbB); STAGE_B(nxtb, k0n, rbB + 128);
        VMCNT(4);                    // retires prev B qn1 (needed by phase 2 reads)
        BARRIER();
        __builtin_amdgcn_s_setprio(1);
#pragma unroll
        for (int i = 0; i < 4; ++i)
#pragma unroll
            for (int j = 0; j < 2; ++j) { MM(4 + i, j, a1[i][0], b0[j][0]); MM(4 + i, j, a1[i][1], b0[j][1]); }
        __builtin_amdgcn_s_setprio(0);

        // ---------- phase 2: quadrant (qm1, qn1) ----------  (no barrier needed)
#pragma unroll
        for (int j = 0; j < 2; ++j) {
            b1[j][0] = *(const bf16x8*)(pB + 2048 + j * 1024 + po);
            b1[j][1] = *(const bf16x8*)(pB + 2048 + j * 1024 + (po ^ 32));
        }
        STAGE_A(nxtb, k0n, 64 + w8); STAGE_A(nxtb, k0n, 192 + w8);
        __builtin_amdgcn_s_setprio(1);
#pragma unroll
        for (int i = 0; i < 4; ++i)
#pragma unroll
            for (int j = 0; j < 2; ++j) { MM(4 + i, 2 + j, a1[i][0], b1[j][0]); MM(4 + i, 2 + j, a1[i][1], b1[j][1]); }
        __builtin_amdgcn_s_setprio(0);

        // ---------- phase 3: quadrant (qm0, qn1) ----------
        STAGE_B(nxtb, k0n, rbB + 32); STAGE_B(nxtb, k0n, rbB + 160);
        VMCNT(4);                    // retires next-tile {A qm0, B qn0} (phase 0 reads)
        BARRIER();
        __builtin_amdgcn_s_setprio(1);
#pragma unroll
        for (int i = 0; i < 4; ++i)
#pragma unroll
            for (int j = 0; j < 2; ++j) { MM(i, 2 + j, a0[i][0], b1[j][0]); MM(i, 2 + j, a0[i][1], b1[j][1]); }
        __builtin_amdgcn_s_setprio(0);
    }

    // ---- peeled last tile (buf = (NT-1)&1 = 1): drain, then compute, no barriers ----
    {
        VMCNT(0);
        BARRIER();
        const unsigned short* pA = sh + 32768 + (wm + fr) * 64;
        const unsigned short* pB = sh + 32768 + 16384 + (wn + fr) * 64;
        bf16x8 a0[4][2], a1[4][2], b0[2][2], b1[2][2];
#pragma unroll
        for (int i = 0; i < 4; ++i) {
            a0[i][0] = *(const bf16x8*)(pA + i * 1024 + po);
            a0[i][1] = *(const bf16x8*)(pA + i * 1024 + (po ^ 32));
            a1[i][0] = *(const bf16x8*)(pA + 4096 + i * 1024 + po);
            a1[i][1] = *(const bf16x8*)(pA + 4096 + i * 1024 + (po ^ 32));
        }
#pragma unroll
        for (int j = 0; j < 2; ++j) {
            b0[j][0] = *(const bf16x8*)(pB + j * 1024 + po);
            b0[j][1] = *(const bf16x8*)(pB + j * 1024 + (po ^ 32));
            b1[j][0] = *(const bf16x8*)(pB + 2048 + j * 1024 + po);
            b1[j][1] = *(const bf16x8*)(pB + 2048 + j * 1024 + (po ^ 32));
        }
#pragma unroll
        for (int i = 0; i < 4; ++i)
#pragma unroll
            for (int j = 0; j < 2; ++j) {
                MM(i, j, a0[i][0], b0[j][0]);         MM(i, j, a0[i][1], b0[j][1]);
                MM(4 + i, j, a1[i][0], b0[j][0]);     MM(4 + i, j, a1[i][1], b0[j][1]);
                MM(4 + i, 2 + j, a1[i][0], b1[j][0]); MM(4 + i, 2 + j, a1[i][1], b1[j][1]);
                MM(i, 2 + j, a0[i][0], b1[j][0]);     MM(i, 2 + j, a0[i][1], b1[j][1]);
            }
    }

    // ---- epilogue: C/D layout col=lane&15, row=(lane>>4)*4+reg  [m89/m91] ----
    const int colb = bn + wn + fr;
    const int rowb = bm + wm + (lane >> 4) * 4;
#pragma unroll
    for (int jg = 0; jg < 4; ++jg) {
        const int col = colb + jg * 16;
        const float bv = bias[col];
#pragma unroll
        for (int ig = 0; ig < 8; ++ig) {
            const int row = rowb + ig * 16;
            float* op = out + (size_t)row * Ndim + col;
#pragma unroll
            for (int r = 0; r < 4; ++r) op[(size_t)r * Ndim] = acc[ig][jg][r] + bv;
        }
    }
#undef MM
#undef STAGE_A
#undef STAGE_B
}

// ---- fallback (only if ws too small): naive fp32, correct but slow ----
__global__ void k_naive(const float* __restrict__ A, const float* __restrict__ W,
                        const float* __restrict__ Msk, const float* __restrict__ bias,
                        float* __restrict__ out) {
    int n = blockIdx.x * blockDim.x + threadIdx.x;
    int m = blockIdx.y;
    if (n >= Ndim) return;
    const float* a = A + (size_t)m * Kdim;
    const float* w = W + (size_t)n * Kdim;
    const float* mk = Msk + (size_t)n * Kdim;
    float s = 0.f;
    for (int k = 0; k < Kdim; ++k) s += a[k] * w[k] * mk[k];
    out[(size_t)m * Ndim + n] = s + bias[n];
}

extern "C" void kernel_launch(void* const* d_in, const int* in_sizes, int n_in,
                              void* d_out, int out_size, void* d_ws, size_t ws_size,
                              hipStream_t stream) {
    const float* data   = (const float*)d_in[0];
    const float* weight = (const float*)d_in[1];
    const float* mask   = (const float*)d_in[2];
    const float* bias   = (const float*)d_in[3];
    float* out = (float*)d_out;

    const size_t needA = (size_t)Mdim * Kdim * 2;  // 64 MiB
    const size_t needB = (size_t)Ndim * Kdim * 2;  // 32 MiB
    if (ws_size < needA + needB) {
        dim3 g((Ndim + 255) / 256, Mdim);
        k_naive<<<g, 256, 0, stream>>>(data, weight, mask, bias, out);
        return;
    }

    unsigned short* Abf = (unsigned short*)d_ws;
    unsigned short* Bbf = Abf + (size_t)Mdim * Kdim;

    k_cvt_all<<<4096, 256, 0, stream>>>((const float4*)data, (const float4*)weight,
                                        (const float4*)mask, (uint4*)Abf, (uint4*)Bbf);

    // 512 blocks (32 M-tiles x 16 N-tiles), 512 threads, 128 KiB LDS -> 1 block/CU
    k_gemm256<<<dim3(512), dim3(512), 0, stream>>>(Abf, Bbf, bias, out);
}